// Round 3
// baseline (1848.447 us; speedup 1.0000x reference)
//
#include <hip/hip_runtime.h>
#include <hip/hip_bf16.h>
#include <hip/hip_fp16.h>

#define T_ 2048
#define B_ 64
#define NIN_ 128
#define H_ 256
#define NOUT_ 128
#define TB_ (T_*B_)

typedef _Float16 h8 __attribute__((ext_vector_type(8)));
typedef _Float16 h4 __attribute__((ext_vector_type(4)));
typedef float f32x4 __attribute__((ext_vector_type(4)));

// load 8 consecutive f32 and convert to 8 f16 (two dwordx4 loads)
__device__ __forceinline__ h8 ld_cvt8(const float* __restrict__ p) {
    const float4* q = (const float4*)p;
    float4 a = q[0], b = q[1];
    h8 r;
    r[0] = (_Float16)a.x; r[1] = (_Float16)a.y; r[2] = (_Float16)a.z; r[3] = (_Float16)a.w;
    r[4] = (_Float16)b.x; r[5] = (_Float16)b.y; r[6] = (_Float16)b.z; r[7] = (_Float16)b.w;
    return r;
}

// ---------------------------------------------------------------------------
// K1: xp[TB][256](f16) = x[TB][128](f32) @ W_ih^T + (b_ih+b_hh)
// C^T MFMA form: A = W_ih[col][k] (static frags), B = x^T (from x rows).
// 512 WGs x 16 row-tile iterations; 16 rows x 256 cols per iteration.
// ---------------------------------------------------------------------------
__global__ __launch_bounds__(256, 2) void k1_xproj(
    const float* __restrict__ x,
    const float* __restrict__ w_ih,
    const float* __restrict__ b_ih,
    const float* __restrict__ b_hh,
    _Float16* __restrict__ xp)
{
    const int tid = threadIdx.x;
    const int lane = tid & 63, wave = tid >> 6;
    const int m = lane & 15, quad = lane >> 4;

    // A-frags: af[i][kt] holds W_ih[col = wave*64+i*16+m][kt*32 + quad*8 ..+7]
    h8 af[4][4];
    #pragma unroll
    for (int i = 0; i < 4; ++i)
        #pragma unroll
        for (int kt = 0; kt < 4; ++kt)
            af[i][kt] = ld_cvt8(w_ih + (size_t)(wave*64 + i*16 + m) * NIN_ + kt*32 + quad*8);

    float bias[4][4];
    #pragma unroll
    for (int i = 0; i < 4; ++i)
        #pragma unroll
        for (int r = 0; r < 4; ++r) {
            int c = wave*64 + i*16 + quad*4 + r;
            bias[i][r] = b_ih[c] + b_hh[c];
        }

    __shared__ __align__(16) _Float16 st[16][264];

    for (int rt = 0; rt < 16; ++rt) {
        const int n0 = blockIdx.x * 256 + rt * 16;   // 16 rows this iter

        // B-frags: bf[kt] = x[n0+m][kt*32+quad*8 ..+7] (f32 -> f16)
        h8 bf[4];
        #pragma unroll
        for (int kt = 0; kt < 4; ++kt)
            bf[kt] = ld_cvt8(x + (size_t)(n0 + m) * NIN_ + kt*32 + quad*8);

        f32x4 acc[4];
        #pragma unroll
        for (int i = 0; i < 4; ++i) acc[i] = (f32x4){0,0,0,0};
        #pragma unroll
        for (int i = 0; i < 4; ++i)
            #pragma unroll
            for (int kt = 0; kt < 4; ++kt)
                acc[i] = __builtin_amdgcn_mfma_f32_16x16x32_f16(af[i][kt], bf[kt], acc[i], 0, 0, 0);

        // epilogue: value (row n0+m, col wave*64+i*16+quad*4+r)
        #pragma unroll
        for (int i = 0; i < 4; ++i) {
            h4 hv;
            #pragma unroll
            for (int r = 0; r < 4; ++r) hv[r] = (_Float16)(acc[i][r] + bias[i][r]);
            *(uint2*)&st[m][wave*64 + i*16 + quad*4] = __builtin_bit_cast(uint2, hv);
        }
        __syncthreads();
        // coalesced writeout: 16 rows x 256 f16 = 512 uint4
        #pragma unroll
        for (int it = 0; it < 2; ++it) {
            int idx = tid + it*256;
            int r = idx >> 5, c8 = (idx & 31) * 8;
            uint4 v = *(const uint4*)&st[r][c8];
            *(uint4*)(xp + (size_t)(n0 + r) * H_ + c8) = v;
        }
        __syncthreads();
    }
}

// ---------------------------------------------------------------------------
// K2: sequential scan, MFMA. 8 WGs x 8 batch, 256 threads (4 waves).
// C^T[j][m] = sum_k W_hh[j][k] h[m][k];  W_hh static in VGPRs (A-frags),
// h double-buffered in LDS [16][264] f16 (B-frags, 8x ds_read_b128/wave,
// rows duplicated m&7 -> 2-way broadcast). One barrier per step.
// ---------------------------------------------------------------------------
__global__ __launch_bounds__(256, 1) void k2_scan(
    const _Float16* __restrict__ xp,       // [T][B][H] f16
    const float* __restrict__ w_hh,        // [H][H] f32
    _Float16* __restrict__ hs)             // [T][B][H] f16
{
    const int tid = threadIdx.x;
    const int lane = tid & 63, wave = tid >> 6;
    const int m = lane & 15, quad = lane >> 4;
    const int mr = m & 7;                   // duplicated batch row for reads
    const int b0 = blockIdx.x * 8;          // 8 real batches per WG
    const bool wr = (m < 8);

    // A-frags: wf[i][kt] = W_hh[j = wave*64+i*16+m][kt*32+quad*8 ..+7]
    h8 wf[4][8];
    #pragma unroll
    for (int i = 0; i < 4; ++i)
        #pragma unroll
        for (int kt = 0; kt < 8; ++kt)
            wf[i][kt] = ld_cvt8(w_hh + (size_t)(wave*64 + i*16 + m) * H_ + kt*32 + quad*8);

    __shared__ __align__(16) _Float16 hb[2][16][264];
    {
        unsigned int* z = (unsigned int*)&hb[0][0][0];
        for (int i = tid; i < 16*264/2; i += 256) z[i] = 0u;
    }
    __syncthreads();

    const int colbase = wave*64 + quad*4;   // j base for (i, reg)
    const _Float16* xpl = xp + (size_t)(b0 + mr) * H_ + colbase;
    _Float16*       hsl = hs + (size_t)(b0 + m)  * H_ + colbase;

    uint2 pf[2][4];
    #pragma unroll
    for (int i = 0; i < 4; ++i) pf[0][i] = *(const uint2*)(xpl + (size_t)0 * (B_*H_) + i*16);
    #pragma unroll
    for (int i = 0; i < 4; ++i) pf[1][i] = *(const uint2*)(xpl + (size_t)1 * (B_*H_) + i*16);

#define K2_STEP(T, RB, WB, P)                                                      \
    {                                                                              \
        h8 bf[8];                                                                  \
        const _Float16* hrow = &RB[mr][0];                                         \
        _Pragma("unroll")                                                          \
        for (int kt = 0; kt < 8; ++kt)                                             \
            bf[kt] = *(const h8*)(hrow + kt*32 + quad*8);                          \
        f32x4 acc[4];                                                              \
        _Pragma("unroll")                                                          \
        for (int i = 0; i < 4; ++i) acc[i] = (f32x4){0,0,0,0};                     \
        _Pragma("unroll")                                                          \
        for (int i = 0; i < 4; ++i)                                                \
            _Pragma("unroll")                                                      \
            for (int kt = 0; kt < 8; ++kt)                                         \
                acc[i] = __builtin_amdgcn_mfma_f32_16x16x32_f16(wf[i][kt], bf[kt], acc[i], 0, 0, 0); \
        const int tn = ((T) + 2 < T_) ? (T) + 2 : T_ - 1;                          \
        uint2 nf[4];                                                               \
        _Pragma("unroll")                                                          \
        for (int i = 0; i < 4; ++i)                                                \
            nf[i] = *(const uint2*)(xpl + (size_t)tn * (B_*H_) + i*16);            \
        _Pragma("unroll")                                                          \
        for (int i = 0; i < 4; ++i) {                                              \
            h4 xh = __builtin_bit_cast(h4, pf[P][i]);                              \
            h4 hv;                                                                 \
            _Pragma("unroll")                                                      \
            for (int r = 0; r < 4; ++r) {                                          \
                float s = acc[i][r] + (float)xh[r];                                \
                float e = __expf(2.0f * s);                                        \
                float hn = fmaf(-2.0f, __builtin_amdgcn_rcpf(e + 1.0f), 1.0f);     \
                hv[r] = (_Float16)hn;                                              \
            }                                                                      \
            *(uint2*)&WB[m][colbase + i*16] = __builtin_bit_cast(uint2, hv);       \
            if (wr) *(uint2*)(hsl + (size_t)(T) * (B_*H_) + i*16) =                \
                __builtin_bit_cast(uint2, hv);                                     \
        }                                                                          \
        _Pragma("unroll")                                                          \
        for (int i = 0; i < 4; ++i) pf[P][i] = nf[i];                              \
        __syncthreads();                                                           \
    }

    for (int t = 0; t < T_; t += 2) {
        K2_STEP(t,     hb[0], hb[1], 0)
        K2_STEP(t + 1, hb[1], hb[0], 1)
    }
#undef K2_STEP
}

// ---------------------------------------------------------------------------
// K3: out[TB][128](f32) = hs[TB][256](f16) @ W_out^T + b_out
// C^T MFMA form: A = W_out[o][k] static frags; B = hs rows (global b128).
// 512 WGs x 16 row-tile iterations.
// ---------------------------------------------------------------------------
__global__ __launch_bounds__(256, 2) void k3_out(
    const _Float16* __restrict__ hs,
    const float* __restrict__ w_out,
    const float* __restrict__ b_out,
    float* __restrict__ out)
{
    const int tid = threadIdx.x;
    const int lane = tid & 63, wave = tid >> 6;
    const int m = lane & 15, quad = lane >> 4;

    // A-frags: af[i][kt] = W_out[o = wave*32+i*16+m][kt*32+quad*8 ..+7]
    h8 af[2][8];
    #pragma unroll
    for (int i = 0; i < 2; ++i)
        #pragma unroll
        for (int kt = 0; kt < 8; ++kt)
            af[i][kt] = ld_cvt8(w_out + (size_t)(wave*32 + i*16 + m) * H_ + kt*32 + quad*8);

    float bias[2][4];
    #pragma unroll
    for (int i = 0; i < 2; ++i)
        #pragma unroll
        for (int r = 0; r < 4; ++r)
            bias[i][r] = b_out[wave*32 + i*16 + quad*4 + r];

    __shared__ __align__(16) float st[16][132];

    for (int rt = 0; rt < 16; ++rt) {
        const int n0 = blockIdx.x * 256 + rt * 16;

        h8 bf[8];
        #pragma unroll
        for (int kt = 0; kt < 8; ++kt)
            bf[kt] = *(const h8*)(hs + (size_t)(n0 + m) * H_ + kt*32 + quad*8);

        f32x4 acc[2];
        #pragma unroll
        for (int i = 0; i < 2; ++i) acc[i] = (f32x4){0,0,0,0};
        #pragma unroll
        for (int i = 0; i < 2; ++i)
            #pragma unroll
            for (int kt = 0; kt < 8; ++kt)
                acc[i] = __builtin_amdgcn_mfma_f32_16x16x32_f16(af[i][kt], bf[kt], acc[i], 0, 0, 0);

        #pragma unroll
        for (int i = 0; i < 2; ++i) {
            f32x4 v;
            #pragma unroll
            for (int r = 0; r < 4; ++r) v[r] = acc[i][r] + bias[i][r];
            *(f32x4*)&st[m][wave*32 + i*16 + quad*4] = v;
        }
        __syncthreads();
        // coalesced writeout: 16 rows x 128 f32 = 512 float4
        #pragma unroll
        for (int it = 0; it < 2; ++it) {
            int idx = tid + it*256;
            int r = idx >> 5, c4 = (idx & 31) * 4;
            f32x4 v = *(const f32x4*)&st[r][c4];
            *(f32x4*)(out + (size_t)(n0 + r) * NOUT_ + c4) = v;
        }
        __syncthreads();
    }
}

extern "C" void kernel_launch(void* const* d_in, const int* in_sizes, int n_in,
                              void* d_out, int out_size, void* d_ws, size_t ws_size,
                              hipStream_t stream) {
    const float* x     = (const float*)d_in[0];
    const float* w_ih  = (const float*)d_in[1];
    const float* w_hh  = (const float*)d_in[2];
    const float* b_ih  = (const float*)d_in[3];
    const float* b_hh  = (const float*)d_in[4];
    const float* w_out = (const float*)d_in[5];
    const float* b_out = (const float*)d_in[6];

    _Float16* xp    = (_Float16*)d_ws;                 // 67.1 MB
    _Float16* hsbuf = xp + (size_t)TB_ * H_;           // 67.1 MB

    k1_xproj<<<512, 256, 0, stream>>>(x, w_ih, b_ih, b_hh, xp);
    k2_scan <<<8,   256, 0, stream>>>(xp, w_hh, hsbuf);
    k3_out  <<<512, 256, 0, stream>>>(hsbuf, w_out, b_out, (float*)d_out);
}

// Round 4
// 1108.903 us; speedup vs baseline: 1.6669x; 1.6669x over previous
//
#include <hip/hip_runtime.h>
#include <hip/hip_bf16.h>
#include <hip/hip_fp16.h>

#define T_ 2048
#define B_ 64
#define NIN_ 128
#define H_ 256
#define NOUT_ 128
#define TB_ (T_*B_)

typedef _Float16 h8 __attribute__((ext_vector_type(8)));
typedef _Float16 h4 __attribute__((ext_vector_type(4)));
typedef _Float16 half2_t __attribute__((ext_vector_type(2)));
typedef float f32x4 __attribute__((ext_vector_type(4)));

__device__ __forceinline__ half2_t mk2(_Float16 a, _Float16 b) { half2_t r; r.x = a; r.y = b; return r; }
__device__ __forceinline__ half2_t f2h2(float a, float b) { return mk2((_Float16)a, (_Float16)b); }
__device__ __forceinline__ float fdot2(half2_t a, half2_t b, float c) {
    return __builtin_amdgcn_fdot2(a, b, c, false);
}
// load 8 consecutive f32 and convert to 8 f16 (two dwordx4 loads)
__device__ __forceinline__ h8 ld_cvt8(const float* __restrict__ p) {
    const float4* q = (const float4*)p;
    float4 a = q[0], b = q[1];
    h8 r;
    r[0] = (_Float16)a.x; r[1] = (_Float16)a.y; r[2] = (_Float16)a.z; r[3] = (_Float16)a.w;
    r[4] = (_Float16)b.x; r[5] = (_Float16)b.y; r[6] = (_Float16)b.z; r[7] = (_Float16)b.w;
    return r;
}
// quad_perm butterfly adds on the VALU pipe (no LDS traffic)
__device__ __forceinline__ float dpp_xor1_add(float x) {
    int y = __builtin_amdgcn_mov_dpp(__builtin_bit_cast(int, x), 0xB1, 0xF, 0xF, true);
    return x + __builtin_bit_cast(float, y);
}
__device__ __forceinline__ float dpp_xor2_add(float x) {
    int y = __builtin_amdgcn_mov_dpp(__builtin_bit_cast(int, x), 0x4E, 0xF, 0xF, true);
    return x + __builtin_bit_cast(float, y);
}

// ---------------------------------------------------------------------------
// K1: xp[TB][256](f16) = x[TB][128](f32) @ W_ih^T + (b_ih+b_hh)   (MFMA C^T)
// ---------------------------------------------------------------------------
__global__ __launch_bounds__(256, 2) void k1_xproj(
    const float* __restrict__ x,
    const float* __restrict__ w_ih,
    const float* __restrict__ b_ih,
    const float* __restrict__ b_hh,
    _Float16* __restrict__ xp)
{
    const int tid = threadIdx.x;
    const int lane = tid & 63, wave = tid >> 6;
    const int m = lane & 15, quad = lane >> 4;

    h8 af[4][4];
    #pragma unroll
    for (int i = 0; i < 4; ++i)
        #pragma unroll
        for (int kt = 0; kt < 4; ++kt)
            af[i][kt] = ld_cvt8(w_ih + (size_t)(wave*64 + i*16 + m) * NIN_ + kt*32 + quad*8);

    float bias[4][4];
    #pragma unroll
    for (int i = 0; i < 4; ++i)
        #pragma unroll
        for (int r = 0; r < 4; ++r) {
            int c = wave*64 + i*16 + quad*4 + r;
            bias[i][r] = b_ih[c] + b_hh[c];
        }

    __shared__ __align__(16) _Float16 st[16][264];

    for (int rt = 0; rt < 16; ++rt) {
        const int n0 = blockIdx.x * 256 + rt * 16;

        h8 bf[4];
        #pragma unroll
        for (int kt = 0; kt < 4; ++kt)
            bf[kt] = ld_cvt8(x + (size_t)(n0 + m) * NIN_ + kt*32 + quad*8);

        f32x4 acc[4];
        #pragma unroll
        for (int i = 0; i < 4; ++i) acc[i] = (f32x4){0,0,0,0};
        #pragma unroll
        for (int i = 0; i < 4; ++i)
            #pragma unroll
            for (int kt = 0; kt < 4; ++kt)
                acc[i] = __builtin_amdgcn_mfma_f32_16x16x32_f16(af[i][kt], bf[kt], acc[i], 0, 0, 0);

        #pragma unroll
        for (int i = 0; i < 4; ++i) {
            h4 hv;
            #pragma unroll
            for (int r = 0; r < 4; ++r) hv[r] = (_Float16)(acc[i][r] + bias[i][r]);
            *(uint2*)&st[m][wave*64 + i*16 + quad*4] = __builtin_bit_cast(uint2, hv);
        }
        __syncthreads();
        #pragma unroll
        for (int it = 0; it < 2; ++it) {
            int idx = tid + it*256;
            int r = idx >> 5, c8 = (idx & 31) * 8;
            uint4 v = *(const uint4*)&st[r][c8];
            *(uint4*)(xp + (size_t)(n0 + r) * H_ + c8) = v;
        }
        __syncthreads();
    }
}

// ---------------------------------------------------------------------------
// K2: sequential scan. 64 WGs (one batch each), 256 threads.
// k-split x4: lane = jg*4+ks; thread computes 4 partial outputs
// j0=wave*64+jg*4 .. +3 over k-slice [ks*64, ks*64+64).
// LDS: h double-buffered, 4 chunks of 64 f16 padded to 72 (16B apart) so the
// 4 broadcast addresses per b128 hit disjoint banks. DPP quad-reduce, then
// lane owns output j = wave*64+lane. One barrier/step.
// ---------------------------------------------------------------------------
__global__ __launch_bounds__(256, 1) void k2_scan(
    const _Float16* __restrict__ xp,       // [T][B][H] f16
    const float* __restrict__ w_hh,        // [H][H] f32
    _Float16* __restrict__ hs)             // [T][B][H] f16
{
    const int tid = threadIdx.x;
    const int lane = tid & 63, wave = tid >> 6;
    const int jg = lane >> 2, ks = lane & 3;
    const int b = blockIdx.x;
    const int j0 = wave*64 + jg*4;          // 4 outputs j0..j0+3 (partial)
    const int jf = wave*64 + lane;          // final owned output after reduce

    // weights: w2[r][p] = W_hh[j0+r][ks*64 + 2p .. +1]  (128 half2 VGPRs)
    half2_t w2[4][32];
    #pragma unroll
    for (int r = 0; r < 4; ++r) {
        const float4* wr = (const float4*)(w_hh + (size_t)(j0 + r) * H_ + ks*64);
        #pragma unroll
        for (int q = 0; q < 16; ++q) {
            float4 d = wr[q];
            w2[r][2*q]   = f2h2(d.x, d.y);
            w2[r][2*q+1] = f2h2(d.z, d.w);
        }
    }

    // h buffers: 2 x 4 chunks x 72 f16 (64 data + 8 pad)
    __shared__ __align__(16) _Float16 hb[2][288];
    {
        unsigned int* z = (unsigned int*)&hb[0][0];
        if (tid < 288) z[tid] = 0u;          // zero both buffers (2*288 f16 = 288 dwords)
    }
    __syncthreads();

    const _Float16* xpl = xp + (size_t)b * H_ + jf;
    _Float16*       hsl = hs + (size_t)b * H_ + jf;

    _Float16 pf[4];
    #pragma unroll
    for (int i = 0; i < 4; ++i) pf[i] = xpl[(size_t)i * (B_*H_)];

#define K2_STEP(T, RB, WB)                                                     \
    {                                                                          \
        const h8* hp = (const h8*)(&RB[ks*72]);                                \
        h8 bv[8];                                                              \
        _Pragma("unroll")                                                      \
        for (int i = 0; i < 8; ++i) bv[i] = hp[i];                             \
        float acc[4][2] = {{0,0},{0,0},{0,0},{0,0}};                           \
        _Pragma("unroll")                                                      \
        for (int i = 0; i < 8; ++i) {                                          \
            const half2_t* hh = (const half2_t*)&bv[i];                        \
            _Pragma("unroll")                                                  \
            for (int r = 0; r < 4; ++r) {                                      \
                acc[r][i&1] = fdot2(hh[0], w2[r][4*i+0], acc[r][i&1]);         \
                acc[r][i&1] = fdot2(hh[1], w2[r][4*i+1], acc[r][i&1]);         \
                acc[r][i&1] = fdot2(hh[2], w2[r][4*i+2], acc[r][i&1]);         \
                acc[r][i&1] = fdot2(hh[3], w2[r][4*i+3], acc[r][i&1]);         \
            }                                                                  \
        }                                                                      \
        const int tn = ((T) + 4 < T_) ? (T) + 4 : T_ - 1;                      \
        _Float16 nf = xpl[(size_t)tn * (B_*H_)];                               \
        float s0 = dpp_xor2_add(dpp_xor1_add(acc[0][0] + acc[0][1]));          \
        float s1 = dpp_xor2_add(dpp_xor1_add(acc[1][0] + acc[1][1]));          \
        float s2 = dpp_xor2_add(dpp_xor1_add(acc[2][0] + acc[2][1]));          \
        float s3 = dpp_xor2_add(dpp_xor1_add(acc[3][0] + acc[3][1]));          \
        float v01 = (ks & 1) ? s1 : s0;                                        \
        float v23 = (ks & 1) ? s3 : s2;                                        \
        float sv  = (ks & 2) ? v23 : v01;                                      \
        sv += (float)pf[(T) & 3];                                              \
        pf[(T) & 3] = nf;                                                      \
        float e  = __expf(2.0f * sv);                                          \
        float hn = fmaf(-2.0f, __builtin_amdgcn_rcpf(e + 1.0f), 1.0f);         \
        _Float16 hh16 = (_Float16)hn;                                          \
        WB[wave*72 + lane] = hh16;                                             \
        hsl[(size_t)(T) * (B_*H_)] = hh16;                                     \
        __syncthreads();                                                       \
    }

    for (int t = 0; t < T_; t += 2) {
        K2_STEP(t,     hb[0], hb[1])
        K2_STEP(t + 1, hb[1], hb[0])
    }
#undef K2_STEP
}

// ---------------------------------------------------------------------------
// K3: out[TB][128](f32) = hs[TB][256](f16) @ W_out^T + b_out   (MFMA C^T)
// ---------------------------------------------------------------------------
__global__ __launch_bounds__(256, 2) void k3_out(
    const _Float16* __restrict__ hs,
    const float* __restrict__ w_out,
    const float* __restrict__ b_out,
    float* __restrict__ out)
{
    const int tid = threadIdx.x;
    const int lane = tid & 63, wave = tid >> 6;
    const int m = lane & 15, quad = lane >> 4;

    h8 af[2][8];
    #pragma unroll
    for (int i = 0; i < 2; ++i)
        #pragma unroll
        for (int kt = 0; kt < 8; ++kt)
            af[i][kt] = ld_cvt8(w_out + (size_t)(wave*32 + i*16 + m) * H_ + kt*32 + quad*8);

    float bias[2][4];
    #pragma unroll
    for (int i = 0; i < 2; ++i)
        #pragma unroll
        for (int r = 0; r < 4; ++r)
            bias[i][r] = b_out[wave*32 + i*16 + quad*4 + r];

    __shared__ __align__(16) float st[16][132];

    for (int rt = 0; rt < 16; ++rt) {
        const int n0 = blockIdx.x * 256 + rt * 16;

        h8 bf[8];
        #pragma unroll
        for (int kt = 0; kt < 8; ++kt)
            bf[kt] = *(const h8*)(hs + (size_t)(n0 + m) * H_ + kt*32 + quad*8);

        f32x4 acc[2];
        #pragma unroll
        for (int i = 0; i < 2; ++i) acc[i] = (f32x4){0,0,0,0};
        #pragma unroll
        for (int i = 0; i < 2; ++i)
            #pragma unroll
            for (int kt = 0; kt < 8; ++kt)
                acc[i] = __builtin_amdgcn_mfma_f32_16x16x32_f16(af[i][kt], bf[kt], acc[i], 0, 0, 0);

        #pragma unroll
        for (int i = 0; i < 2; ++i) {
            f32x4 v;
            #pragma unroll
            for (int r = 0; r < 4; ++r) v[r] = acc[i][r] + bias[i][r];
            *(f32x4*)&st[m][wave*32 + i*16 + quad*4] = v;
        }
        __syncthreads();
        #pragma unroll
        for (int it = 0; it < 2; ++it) {
            int idx = tid + it*256;
            int r = idx >> 5, c4 = (idx & 31) * 4;
            f32x4 v = *(const f32x4*)&st[r][c4];
            *(f32x4*)(out + (size_t)(n0 + r) * NOUT_ + c4) = v;
        }
        __syncthreads();
    }
}

extern "C" void kernel_launch(void* const* d_in, const int* in_sizes, int n_in,
                              void* d_out, int out_size, void* d_ws, size_t ws_size,
                              hipStream_t stream) {
    const float* x     = (const float*)d_in[0];
    const float* w_ih  = (const float*)d_in[1];
    const float* w_hh  = (const float*)d_in[2];
    const float* b_ih  = (const float*)d_in[3];
    const float* b_hh  = (const float*)d_in[4];
    const float* w_out = (const float*)d_in[5];
    const float* b_out = (const float*)d_in[6];

    _Float16* xp    = (_Float16*)d_ws;                 // 67.1 MB
    _Float16* hsbuf = xp + (size_t)TB_ * H_;           // 67.1 MB

    k1_xproj<<<512, 256, 0, stream>>>(x, w_ih, b_ih, b_hh, xp);
    k2_scan <<<B_,  256, 0, stream>>>(xp, w_hh, hsbuf);
    k3_out  <<<512, 256, 0, stream>>>(hsbuf, w_out, b_out, (float*)d_out);
}